// Round 12
// baseline (505.061 us; speedup 1.0000x reference)
//
#include <hip/hip_runtime.h>
#include <hip/hip_bf16.h>

typedef unsigned short u16;
typedef unsigned int u32;
typedef __attribute__((ext_vector_type(8))) short short8;
typedef __attribute__((ext_vector_type(4))) float f32x4;

#define B_ 4
#define T_ 2048
#define D_ 1024
#define H_ 16
#define HS_ 64
#define BT (B_*T_)

__device__ __forceinline__ float bf2f(u16 b){ union{u32 u; float f;} v; v.u=((u32)b)<<16; return v.f; }
__device__ __forceinline__ u16 f2bf(float f){
    __hip_bfloat16 h = __float2bfloat16(f);
    union{__hip_bfloat16 h; u16 u;} v; v.h = h; return v.u;
}
// split f32 into hi/lo bf16: x ~= hi + lo
__device__ __forceinline__ void split2(float x, u16& h, u16& l){
    u16 hb = f2bf(x);
    float fh = bf2f(hb);
    h = hb; l = f2bf(x - fh);
}
union U4 { u16 s[4]; uint2 v; };
union S8 { u16 s[8]; short8 v; };

// async global->LDS, 16B per lane; LDS dest wave-linear (base + lane*16)
#define GLD16(g,l) __builtin_amdgcn_global_load_lds( \
    (__attribute__((address_space(1))) void*)(u16*)(g), \
    (__attribute__((address_space(3))) void*)(l), 16, 0, 0)

// XOR-swizzled offset into a row-major [R][64]-u16 LDS tile, 16B-chunk granularity.
__device__ __forceinline__ int swz(int row, int col){
    return row*64 + (((col>>3) ^ (row&7))<<3) + (col&7);
}
// chunk-swizzle for the GEMM [128][32]-u16 tiles (64B rows, 4 x 16B chunks).
// Proven: SQ_LDS_BANK_CONFLICT 12.6M -> 0 (round 4).
#define FCHK(r) (((r)>>1)&3)

// ---- pack: Wt[n][d] (split hi/lo) = W_z[h][d][e], n = z*1024 + h*64 + e ----
__global__ __launch_bounds__(256) void pack_w(const float* __restrict__ Wq,
                                              const float* __restrict__ Wk,
                                              const float* __restrict__ Wv,
                                              u16* __restrict__ Wth,
                                              u16* __restrict__ Wtl)
{
    __shared__ float Tl[64*68];
    const int h = blockIdx.x, dt = blockIdx.y, z = blockIdx.z;
    const float* src = (z==0) ? Wq : ((z==1) ? Wk : Wv);
    const int t = threadIdx.x;
    const int d0 = dt*64;
    #pragma unroll
    for (int i=0;i<4;++i){
        int ci = t + 256*i;
        int dr = ci>>4, ec = ci&15;
        float4 v = *(const float4*)(src + ((size_t)h*D_ + d0+dr)*HS_ + ec*4);
        *(float4*)(Tl + dr*68 + ec*4) = v;
    }
    __syncthreads();
    #pragma unroll
    for (int i=0;i<4;++i){
        int ci = t + 256*i;
        int e = ci>>4, dc = ci&15;
        U4 hh, ll;
        #pragma unroll
        for (int j=0;j<4;++j){
            float f = Tl[(dc*4+j)*68 + e];
            split2(f, hh.s[j], ll.s[j]);
        }
        int n = z*D_ + h*HS_ + e;
        *(uint2*)(Wth + (size_t)n*D_ + d0 + dc*4) = hh.v;
        *(uint2*)(Wtl + (size_t)n*D_ + d0 + dc*4) = ll.v;
    }
}

// ---- QKV GEMM: qkv[t][col] = x[t][:]·Wt[col][:], col in [0,3072) ----
// LDS chunk-swizzled (FCHK): B via pre-swizzled GLOBAL source, A via swizzled ds_write.
__global__ __launch_bounds__(256) void gemm_qkv(const float* __restrict__ x,
                                                const u16* __restrict__ Wth,
                                                const u16* __restrict__ Wtl,
                                                float* __restrict__ qo,
                                                u16* __restrict__ kho, u16* __restrict__ klo,
                                                u16* __restrict__ vth, u16* __restrict__ vtl)
{
    __shared__ u16 Ash[128*32], Asl[128*32];
    __shared__ u16 Bsh[128*32], Bsl[128*32];
    const int n0 = blockIdx.x*128, m0 = blockIdx.y*128;
    const int t = threadIdx.x;
    const int w = t>>6, lane = t&63, quad = lane>>4, l16 = lane&15;
    const int wm = (w>>1)*64, wn = (w&1)*64;
    f32x4 acc[4][4];
    #pragma unroll
    for (int i=0;i<4;++i)
        #pragma unroll
        for (int j=0;j<4;++j) acc[i][j] = (f32x4){0.f,0.f,0.f,0.f};
    for (int kt=0; kt<32; ++kt){
        const int k0 = kt*32;
        #pragma unroll
        for (int i=0;i<2;++i){           // B: async 16B chunks, pre-swizzled source
            int ci = t + 256*i;
            int row = ci>>2, c = ci&3;
            int cs = c ^ FCHK(row);
            GLD16(Wth + (size_t)(n0+row)*D_ + k0 + cs*8, Bsh + ci*8);
            GLD16(Wtl + (size_t)(n0+row)*D_ + k0 + cs*8, Bsl + ci*8);
        }
        #pragma unroll
        for (int i=0;i<4;++i){           // A: f32 load + split, swizzled ds_write
            int ci = t + 256*i;
            int row = ci>>3, c4 = ci&7;
            float4 av = *(const float4*)(x + (size_t)(m0+row)*D_ + k0 + c4*4);
            U4 hh, ll;
            split2(av.x, hh.s[0], ll.s[0]); split2(av.y, hh.s[1], ll.s[1]);
            split2(av.z, hh.s[2], ll.s[2]); split2(av.w, hh.s[3], ll.s[3]);
            int off = row*32 + ((((c4>>1) ^ FCHK(row))<<3) | ((c4&1)<<2));
            *(uint2*)(Ash + off) = hh.v;
            *(uint2*)(Asl + off) = ll.v;
        }
        __syncthreads();
        short8 afh[4], afl[4], bfh[4], bfl[4];
        #pragma unroll
        for (int mi=0;mi<4;++mi){
            const int rr = wm+mi*16+l16;
            const int off = rr*32 + ((quad ^ FCHK(rr))<<3);
            afh[mi] = *(const short8*)(Ash + off);
            afl[mi] = *(const short8*)(Asl + off);
        }
        #pragma unroll
        for (int ni=0;ni<4;++ni){
            const int rr = wn+ni*16+l16;
            const int off = rr*32 + ((quad ^ FCHK(rr))<<3);
            bfh[ni] = *(const short8*)(Bsh + off);
            bfl[ni] = *(const short8*)(Bsl + off);
        }
        #pragma unroll
        for (int mi=0;mi<4;++mi)
            #pragma unroll
            for (int ni=0;ni<4;++ni){
                acc[mi][ni] = __builtin_amdgcn_mfma_f32_16x16x32_bf16(afh[mi], bfh[ni], acc[mi][ni], 0,0,0);
                acc[mi][ni] = __builtin_amdgcn_mfma_f32_16x16x32_bf16(afh[mi], bfl[ni], acc[mi][ni], 0,0,0);
                acc[mi][ni] = __builtin_amdgcn_mfma_f32_16x16x32_bf16(afl[mi], bfh[ni], acc[mi][ni], 0,0,0);
            }
        __syncthreads();
    }
    const int z = n0 >> 10;              // block-uniform (128 | 1024)
    if (z == 0){
        #pragma unroll
        for (int ni=0;ni<4;++ni){
            const int nloc = (n0 & 1023) + wn + ni*16 + l16;
            #pragma unroll
            for (int mi=0;mi<4;++mi){
                const int row = m0 + wm + mi*16 + quad*4;
                #pragma unroll
                for (int r=0;r<4;++r)
                    qo[(size_t)(row+r)*D_ + nloc] = acc[mi][ni][r];
            }
        }
    } else if (z == 1){
        #pragma unroll
        for (int ni=0;ni<4;++ni){
            const int nloc = (n0 & 1023) + wn + ni*16 + l16;
            #pragma unroll
            for (int mi=0;mi<4;++mi){
                const int row = m0 + wm + mi*16 + quad*4;
                #pragma unroll
                for (int r=0;r<4;++r){
                    u16 hh, ll; split2(acc[mi][ni][r], hh, ll);
                    kho[(size_t)(row+r)*D_ + nloc] = hh;
                    klo[(size_t)(row+r)*D_ + nloc] = ll;
                }
            }
        }
    } else {
        #pragma unroll
        for (int ni=0;ni<4;++ni){
            const int nloc = (n0 & 1023) + wn + ni*16 + l16;
            const int hloc = nloc>>6, e = nloc&63;
            #pragma unroll
            for (int mi=0;mi<4;++mi){
                const int rowb = m0 + wm + mi*16 + quad*4;   // multiple of 4
                const int bidx = rowb >> 11, tloc = rowb & 2047;
                U4 hh, ll;
                #pragma unroll
                for (int r=0;r<4;++r) split2(acc[mi][ni][r], hh.s[r], ll.s[r]);
                const size_t adr = ((size_t)((bidx*16 + hloc)*64 + e))*T_ + tloc;
                *(uint2*)(vth + adr) = hh.v;
                *(uint2*)(vtl + adr) = ll.v;
            }
        }
    }
}

// ---- causal flash attention, ROUND-12 (= r11 resubmit after container flake):
// MERGED paired q-tiles in ONE kv-loop. Block x processes q-tile A (qi=15-x)
// every iteration and q-tile B (qi=x) while kvt < 2x+2 — both consume the
// SAME staged K/V tile. vs r10:
//  * barriers/block: 34 -> 32-2x (mean 25, -26%); staged bytes -26%.
//  * double-work iterations put TWO independent QK/SM/PV chains in one
//    barrier interval -> latency bubbles of chain A filled by chain B.
//  * total compute/block stays exactly 34 units for every x (balanced).
// Sync structure = r10's proven single-barrier GLD16 dbuf (pre-swizzled
// source, linear dest, swz read). Inner tile body = r9's swapped-QK^T.
// VGPR watch: +2nd q-frag/acc set, est ~120 vs 128 cap of (512,2); spill
// would show as WRITE_SIZE balloon (r1 signature) -> revert trigger. ----
__global__ __launch_bounds__(512, 2) void attn(const float* __restrict__ qf,
                                            const u16* __restrict__ kh, const u16* __restrict__ kl,
                                            const u16* __restrict__ vth, const u16* __restrict__ vtl,
                                            float* __restrict__ att)
{
    __shared__ u16 KshH[2*64*64], KshL[2*64*64];   // dbuf [kv][e], swizzled (32 KB)
    __shared__ u16 VshH[2*64*64], VshL[2*64*64];   // dbuf [e][kv], swizzled (32 KB)
    __shared__ u16 Pb[8*16*64];                    // per-wave [16][64], phased h/l (16 KB)
    const int x = blockIdx.y & 7;            // q-pair index (XCD-grouped remap, r3-proven)
    const int bh = (blockIdx.x << 3) | (blockIdx.y >> 3);
    const int b = bh >> 4, h = bh & 15;
    const int t = threadIdx.x;
    const int w = t>>6, lane = t&63, quad = lane>>4, l16 = lane&15;

    u16* Pm = Pb + w*1024;

    // staging geometry: 512 threads x 1 GLD16 per array = 8 KB/array/tile.
    const int srow = t>>3;                   // row 0..63 (K: kv, V: e)
    const int csrc = (t&7) ^ (srow&7);       // inverse-swz source chunk
    const int ldst = t*8;                    // u16 offset of this thread's 16B slot

    #define STAGE_KV(kvbase, bsel) do{                                         \
        const size_t gk_ = ((size_t)(b*T_ + (kvbase) + srow))*D_ + h*64 + csrc*8; \
        GLD16(kh  + gk_, KshH + (bsel)*4096 + ldst);                           \
        GLD16(kl  + gk_, KshL + (bsel)*4096 + ldst);                           \
        const size_t gv_ = ((size_t)(bh*64 + srow))*T_ + (kvbase) + csrc*8;    \
        GLD16(vth + gv_, VshH + (bsel)*4096 + ldst);                           \
        GLD16(vtl + gv_, VshL + (bsel)*4096 + ldst);                           \
    }while(0)

    int cur = 0;
    STAGE_KV(0, 0);                          // prologue: tile 0 -> buf 0

    const int qiA = 15 - x, qiB = x;
    const int qrowA = qiA*128 + w*16, qrowB = qiB*128 + w*16;
    const int qA_abs = qrowA + l16,   qB_abs = qrowB + l16;

    short8 qAh[2], qAl[2], qBh[2], qBl[2];
    {
        const float* qp = qf + ((size_t)(b*T_ + qrowA + l16))*D_ + h*64;
        #pragma unroll
        for (int ks=0;ks<2;++ks){
            float4 a0 = *(const float4*)(qp + ks*32 + quad*8);
            float4 a1 = *(const float4*)(qp + ks*32 + quad*8 + 4);
            S8 hh, ll;
            split2(a0.x, hh.s[0], ll.s[0]); split2(a0.y, hh.s[1], ll.s[1]);
            split2(a0.z, hh.s[2], ll.s[2]); split2(a0.w, hh.s[3], ll.s[3]);
            split2(a1.x, hh.s[4], ll.s[4]); split2(a1.y, hh.s[5], ll.s[5]);
            split2(a1.z, hh.s[6], ll.s[6]); split2(a1.w, hh.s[7], ll.s[7]);
            qAh[ks] = hh.v; qAl[ks] = ll.v;
        }
    }
    {
        const float* qp = qf + ((size_t)(b*T_ + qrowB + l16))*D_ + h*64;
        #pragma unroll
        for (int ks=0;ks<2;++ks){
            float4 a0 = *(const float4*)(qp + ks*32 + quad*8);
            float4 a1 = *(const float4*)(qp + ks*32 + quad*8 + 4);
            S8 hh, ll;
            split2(a0.x, hh.s[0], ll.s[0]); split2(a0.y, hh.s[1], ll.s[1]);
            split2(a0.z, hh.s[2], ll.s[2]); split2(a0.w, hh.s[3], ll.s[3]);
            split2(a1.x, hh.s[4], ll.s[4]); split2(a1.y, hh.s[5], ll.s[5]);
            split2(a1.z, hh.s[6], ll.s[6]); split2(a1.w, hh.s[7], ll.s[7]);
            qBh[ks] = hh.v; qBl[ks] = ll.v;
        }
    }

    f32x4 oA[4], oB[4];
    #pragma unroll
    for (int i=0;i<4;++i){ oA[i] = (f32x4){0.f,0.f,0.f,0.f}; oB[i] = (f32x4){0.f,0.f,0.f,0.f}; }
    float mA = -INFINITY, lA = 0.f, mB = -INFINITY, lB = 0.f;

    const int kvTA = 2*qiA + 2;              // merged loop length (32-2x)
    const int kvTB = 2*qiB + 2;              // B active while kvt < kvTB

    for (int kvt=0; kvt<kvTA; ++kvt){
        __syncthreads();                     // drains buf[cur] loads; prev readers of buf[cur^1] done
        if (kvt+1 < kvTA) STAGE_KV((kvt+1)*64, cur^1);

        const u16* KH = KshH + cur*4096;
        const u16* KL = KshL + cur*4096;
        const u16* VH = VshH + cur*4096;
        const u16* VL = VshL + cur*4096;

        auto process = [&](const short8* qh_, const short8* ql_,
                           int qrow, int q_abs, f32x4* o, float& m_i, float& l_i){
            // ---- QK^T, SWAPPED: mfma(A=K, B=Q). lane holds q = l16 (col),
            // kv = ni*16 + quad*4 + r (row). ----
            float s[4][4];
            __builtin_amdgcn_s_setprio(1);
            #pragma unroll
            for (int ni=0;ni<4;++ni){
                f32x4 sa = (f32x4){0.f,0.f,0.f,0.f};
                const int row = ni*16 + l16;
                #pragma unroll
                for (int ks=0;ks<2;++ks){
                    const int co = swz(row, ks*32 + quad*8);
                    short8 k8h = *(const short8*)(KH + co);
                    short8 k8l = *(const short8*)(KL + co);
                    sa = __builtin_amdgcn_mfma_f32_16x16x32_bf16(k8h, qh_[ks], sa, 0,0,0);
                    sa = __builtin_amdgcn_mfma_f32_16x16x32_bf16(k8l, qh_[ks], sa, 0,0,0);
                    sa = __builtin_amdgcn_mfma_f32_16x16x32_bf16(k8h, ql_[ks], sa, 0,0,0);
                }
                #pragma unroll
                for (int r=0;r<4;++r) s[ni][r] = sa[r]*0.125f;
            }
            __builtin_amdgcn_s_setprio(0);
            // causal mask: kv > q
            if (kvt*64 + 63 > qrow){
                #pragma unroll
                for (int ni=0;ni<4;++ni){
                    #pragma unroll
                    for (int r=0;r<4;++r){
                        const int kv_abs = kvt*64 + ni*16 + quad*4 + r;
                        if (kv_abs > q_abs) s[ni][r] = -INFINITY;
                    }
                }
            }
            // ---- online softmax, lane-local row + 2-step cross-quad reduce ----
            float rm = s[0][0];
            #pragma unroll
            for (int ni=0;ni<4;++ni)
                #pragma unroll
                for (int r=0;r<4;++r) rm = fmaxf(rm, s[ni][r]);
            rm = fmaxf(rm, __shfl_xor(rm, 16));
            rm = fmaxf(rm, __shfl_xor(rm, 32));
            const float mnew = fmaxf(m_i, rm);
            const float alpha = __expf(m_i - mnew);
            m_i = mnew;
            float rs = 0.f;
            #pragma unroll
            for (int ni=0;ni<4;++ni)
                #pragma unroll
                for (int r=0;r<4;++r){
                    s[ni][r] = __expf(s[ni][r] - mnew);
                    rs += s[ni][r];
                }
            rs += __shfl_xor(rs, 16);
            rs += __shfl_xor(rs, 32);
            l_i = l_i*alpha + rs;
            float a4[4];
            #pragma unroll
            for (int r=0;r<4;++r) a4[r] = __shfl(alpha, quad*4 + r);
            #pragma unroll
            for (int ni=0;ni<4;++ni)
                #pragma unroll
                for (int r=0;r<4;++r) o[ni][r] *= a4[r];

            // ---- P: split once; phased h then l; b64 writes (4 consecutive kv) ----
            uint2 plv[4];
            #pragma unroll
            for (int ni=0;ni<4;++ni){
                U4 hh, ll;
                #pragma unroll
                for (int r=0;r<4;++r) split2(s[ni][r], hh.s[r], ll.s[r]);
                *(uint2*)(Pm + swz(l16, ni*16 + quad*4)) = hh.v;
                plv[ni] = ll.v;
            }
            __asm__ volatile("s_waitcnt lgkmcnt(0)" ::: "memory");
            short8 pah[2], pal[2];
            #pragma unroll
            for (int ks=0;ks<2;++ks)
                pah[ks] = *(const short8*)(Pm + swz(l16, ks*32 + quad*8));
            __asm__ volatile("" ::: "memory");   // keep reads before the l-overwrite
            #pragma unroll
            for (int ni=0;ni<4;++ni)
                *(uint2*)(Pm + swz(l16, ni*16 + quad*4)) = plv[ni];
            __asm__ volatile("s_waitcnt lgkmcnt(0)" ::: "memory");
            #pragma unroll
            for (int ks=0;ks<2;++ks)
                pal[ks] = *(const short8*)(Pm + swz(l16, ks*32 + quad*8));
            __asm__ volatile("" ::: "memory");   // keep reads before next overwrite

            __builtin_amdgcn_s_setprio(1);
            #pragma unroll
            for (int ni=0;ni<4;++ni){
                const int row = ni*16 + l16;
                #pragma unroll
                for (int ks=0;ks<2;++ks){
                    const int co = swz(row, ks*32 + quad*8);
                    short8 v8h = *(const short8*)(VH + co);
                    short8 v8l = *(const short8*)(VL + co);
                    o[ni] = __builtin_amdgcn_mfma_f32_16x16x32_bf16(pah[ks], v8h, o[ni], 0,0,0);
                    o[ni] = __builtin_amdgcn_mfma_f32_16x16x32_bf16(pah[ks], v8l, o[ni], 0,0,0);
                    o[ni] = __builtin_amdgcn_mfma_f32_16x16x32_bf16(pal[ks], v8h, o[ni], 0,0,0);
                }
            }
            __builtin_amdgcn_s_setprio(0);
        };

        process(qAh, qAl, qrowA, qA_abs, oA, mA, lA);
        if (kvt < kvTB)
            process(qBh, qBl, qrowB, qB_abs, oB, mB, lB);
        cur ^= 1;
    }
    #undef STAGE_KV

    // epilogues: o rows are q = quad*4+r; l_i identical across quads per l16
    {
        float lt[4];
        #pragma unroll
        for (int r=0;r<4;++r) lt[r] = __shfl(lA, quad*4 + r);
        const size_t ob = (size_t)(b*T_ + qrowA);
        #pragma unroll
        for (int ni=0;ni<4;++ni){
            const int col = h*64 + ni*16 + l16;
            #pragma unroll
            for (int r=0;r<4;++r)
                att[(ob + quad*4 + r)*D_ + col] = oA[ni][r] / lt[r];
        }
    }
    {
        float lt[4];
        #pragma unroll
        for (int r=0;r<4;++r) lt[r] = __shfl(lB, quad*4 + r);
        const size_t ob = (size_t)(b*T_ + qrowB);
        #pragma unroll
        for (int ni=0;ni<4;++ni){
            const int col = h*64 + ni*16 + l16;
            #pragma unroll
            for (int r=0;r<4;++r)
                att[(ob + quad*4 + r)*D_ + col] = oB[ni][r] / lt[r];
        }
    }
}

// ---- f32-in GEMM (A f32, Bt f32 [N,K], bias) for out-proj; chunk-swizzled LDS ----
__global__ __launch_bounds__(256) void gemm_bt(const float* __restrict__ A,
                                               const float* __restrict__ Bt,
                                               float* __restrict__ C,
                                               const float* __restrict__ bias,
                                               int M, int N, int K)
{
    __shared__ u16 Ash[128*32], Asl[128*32];
    __shared__ u16 Bsh[128*32], Bsl[128*32];
    const int n0 = blockIdx.x*128, m0 = blockIdx.y*128;
    const int t = threadIdx.x;
    const int w = t>>6, lane = t&63, quad = lane>>4, l16 = lane&15;
    const int wm = (w>>1)*64, wn = (w&1)*64;
    f32x4 acc[4][4];
    #pragma unroll
    for (int i=0;i<4;++i)
        #pragma unroll
        for (int j=0;j<4;++j) acc[i][j] = (f32x4){0.f,0.f,0.f,0.f};
    const int kT = K >> 5;
    for (int kt=0; kt<kT; ++kt){
        const int k0 = kt*32;
        #pragma unroll
        for (int i=0;i<4;++i){
            int ci = t + 256*i;
            int row = ci>>3, c4 = ci&7;
            float4 av = *(const float4*)(A  + (size_t)(m0+row)*K + k0 + c4*4);
            float4 bv = *(const float4*)(Bt + (size_t)(n0+row)*K + k0 + c4*4);
            U4 ah, al, bh, bl;
            split2(av.x, ah.s[0], al.s[0]); split2(av.y, ah.s[1], al.s[1]);
            split2(av.z, ah.s[2], al.s[2]); split2(av.w, ah.s[3], al.s[3]);
            split2(bv.x, bh.s[0], bl.s[0]); split2(bv.y, bh.s[1], bl.s[1]);
            split2(bv.z, bh.s[2], bl.s[2]); split2(bv.w, bh.s[3], bl.s[3]);
            int off = row*32 + ((((c4>>1) ^ FCHK(row))<<3) | ((c4&1)<<2));
            *(uint2*)(Ash + off) = ah.v;
            *(uint2*)(Asl + off) = al.v;
            *(uint2*)(Bsh + off) = bh.v;
            *(uint2*)(Bsl + off) = bl.v;
        }
        __syncthreads();
        short8 afh[4], afl[4], bfh[4], bfl[4];
        #pragma unroll
        for (int mi=0;mi<4;++mi){
            const int rr = wm+mi*16+l16;
            const int off = rr*32 + ((quad ^ FCHK(rr))<<3);
            afh[mi] = *(const short8*)(Ash + off);
            afl[mi] = *(const short8*)(Asl + off);
        }
        #pragma unroll
        for (int ni=0;ni<4;++ni){
            const int rr = wn+ni*16+l16;
            const int off = rr*32 + ((quad ^ FCHK(rr))<<3);
            bfh[ni] = *(const short8*)(Bsh + off);
            bfl[ni] = *(const short8*)(Bsl + off);
        }
        #pragma unroll
        for (int mi=0;mi<4;++mi)
            #pragma unroll
            for (int ni=0;ni<4;++ni){
                acc[mi][ni] = __builtin_amdgcn_mfma_f32_16x16x32_bf16(afh[mi], bfh[ni], acc[mi][ni], 0,0,0);
                acc[mi][ni] = __builtin_amdgcn_mfma_f32_16x16x32_bf16(afh[mi], bfl[ni], acc[mi][ni], 0,0,0);
                acc[mi][ni] = __builtin_amdgcn_mfma_f32_16x16x32_bf16(afl[mi], bfh[ni], acc[mi][ni], 0,0,0);
            }
        __syncthreads();
    }
    #pragma unroll
    for (int ni=0;ni<4;++ni){
        const int col = n0 + wn + ni*16 + l16;
        const float bv = bias ? bias[col] : 0.f;
        #pragma unroll
        for (int mi=0;mi<4;++mi){
            const int row = m0 + wm + mi*16 + quad*4;
            #pragma unroll
            for (int r=0;r<4;++r)
                C[(size_t)(row+r)*N + col] = acc[mi][ni][r] + bv;
        }
    }
}

extern "C" void kernel_launch(void* const* d_in, const int* in_sizes, int n_in,
                              void* d_out, int out_size, void* d_ws, size_t ws_size,
                              hipStream_t stream)
{
    const float* x  = (const float*)d_in[0];
    const float* Wq = (const float*)d_in[1];
    const float* Wk = (const float*)d_in[2];
    const float* Wv = (const float*)d_in[3];
    const float* Wp = (const float*)d_in[4];
    const float* bp = (const float*)d_in[5];
    float* out = (float*)d_out;

    // workspace layout (134.2 MB, round-4 proven footprint)
    float* q   = (float*)d_ws;                 // [BT][1024] f32
    u16*  kh   = (u16*)(q + (size_t)BT*D_);    // [BT][1024] u16
    u16*  kl   = kh + (size_t)BT*D_;
    u16*  vth  = kl + (size_t)BT*D_;           // [64bh][64e][2048t] u16
    u16*  vtl  = vth + (size_t)BT*D_;
    float* att = (float*)(vtl + (size_t)BT*D_);// [BT][1024] f32
    // Wt (split) aliases the att region: dead before attn writes att
    u16*  Wth  = (u16*)att;                    // [3072][1024] u16 (6.3 MB)
    u16*  Wtl  = Wth + (size_t)3072*D_;

    pack_w  <<<dim3(16,16,3), 256, 0, stream>>>(Wq, Wk, Wv, Wth, Wtl);
    gemm_qkv<<<dim3(24, BT/128), 256, 0, stream>>>(x, Wth, Wtl, q, kh, kl, vth, vtl);
    attn    <<<dim3(8, 64), 512, 0, stream>>>(q, kh, kl, vth, vtl, att);
    gemm_bt <<<dim3(8, BT/128), 256, 0, stream>>>(att, Wp, out, bp, BT, D_, D_);
}